// Round 6
// baseline (232.425 us; speedup 1.0000x reference)
//
#include <hip/hip_runtime.h>
#include <hip/hip_bf16.h>
#include <math.h>

// GCN 3-layer inference. N=100000, E=3200000, feats 128->4->2->1.
// R6: fully-coalesced CSR build, no slab, zero device atomics.
//  k_hist       : per-chunk LDS histogram over buckets(dst>>8) -> histT.
//  k_scanA/B    : scan histT rows (per-bucket over chunks) + bucket bases.
//  k_sortscatter: LDS counting-sort each 4096-edge chunk, write each bucket
//                 segment to its final bucket-contiguous spot in pairs2
//                 (16-lane group per segment, contiguous runs, no atomics).
//  k_degree2    : per bucket: coalesced read of its pairs2 run -> LDS,
//                 per-node count + scan -> cnt/off/dinv, in-place counting
//                 sort (pairs2 becomes dst-sorted ssrc), scale hs1 *= dinv.
//  k_node1      : 128->4 GEMM (raw h1, dinv applied in k_degree2).
//  k_gather1/2/3: 8 lanes/node over contiguous CSR segment, fused epilogues.
// Edge pack: p = src | (dst&255)<<17  (src < 2^17).

#define TPB 256
#define CHUNK 4096
#define EPT (CHUNK / TPB)
#define SLAB2 9216          // per-bucket LDS capacity (mean 8184, +11 sigma)

// ---- k_hist ----
__global__ __launch_bounds__(TPB) void k_hist(const int* __restrict__ dst,
                                              int* __restrict__ histT,
                                              int NS, int NB, int E) {
    __shared__ int h[512];
    int t = threadIdx.x;
    h[t] = 0; h[t + 256] = 0;
    __syncthreads();
    int base = blockIdx.x * CHUNK, end = min(base + CHUNK, E);
    for (int e = base + t; e < end; e += TPB) atomicAdd(&h[dst[e] >> 8], 1);
    __syncthreads();
    for (int i = t; i < NB; i += TPB) histT[(size_t)i * NS + blockIdx.x] = h[i];
}

// ---- k_scanA: per bucket, exclusive-scan histT row over chunks ----
__global__ __launch_bounds__(TPB) void k_scanA(int* __restrict__ histT,
                                               int* __restrict__ binTotal, int NS) {
    __shared__ int s[TPB];
    int* row = histT + (size_t)blockIdx.x * NS;
    int t = threadIdx.x;
    int run = 0;
    for (int base = 0; base < NS; base += TPB) {
        int i = base + t;
        int v = (i < NS) ? row[i] : 0;
        s[t] = v;
        __syncthreads();
        int x = v;
        for (int d = 1; d < TPB; d <<= 1) {
            int y = (t >= d) ? s[t - d] : 0;
            __syncthreads();
            x += y; s[t] = x;
            __syncthreads();
        }
        if (i < NS) row[i] = run + (x - v);
        run += s[TPB - 1];
        __syncthreads();
    }
    if (t == 0) binTotal[blockIdx.x] = run;
}

// ---- k_scanB: exclusive scan binTotal -> binBase ----
__global__ __launch_bounds__(512) void k_scanB(const int* __restrict__ binTotal,
                                               int* __restrict__ binBase, int NB) {
    __shared__ int s[512];
    int t = threadIdx.x;
    int v = (t < NB) ? binTotal[t] : 0;
    s[t] = v;
    __syncthreads();
    int x = v;
    for (int d = 1; d < 512; d <<= 1) {
        int y = (t >= d) ? s[t - d] : 0;
        __syncthreads();
        x += y; s[t] = x;
        __syncthreads();
    }
    if (t < NB) binBase[t] = x - v;
}

// ---- k_sortscatter: LDS sort chunk, write segments to final positions ----
__global__ __launch_bounds__(TPB) void k_sortscatter(
    const int* __restrict__ src, const int* __restrict__ dst,
    const int* __restrict__ histT, const int* __restrict__ binBase,
    unsigned int* __restrict__ pairs2, int NS, int NB, int E)
{
    __shared__ int hist[512];
    __shared__ int s[TPB];
    __shared__ int gbase[512];
    __shared__ unsigned int sorted[CHUNK];
    int t = threadIdx.x, blk = blockIdx.x;
    int base = blk * CHUNK;
    int n = min(CHUNK, E - base);
    hist[t] = 0; hist[t + 256] = 0;
    for (int i = t; i < NB; i += TPB)
        gbase[i] = binBase[i] + histT[(size_t)i * NS + blk];
    __syncthreads();
    unsigned int meta[EPT];   // d<<13 | lp  (lp < 4096 -> 13 bits)
#pragma unroll
    for (int k = 0; k < EPT; ++k) {
        int li = k * TPB + t;
        if (li < n) {
            int d = dst[base + li];
            int lp = atomicAdd(&hist[d >> 8], 1);
            meta[k] = ((unsigned)d << 13) | (unsigned)lp;
        } else meta[k] = 0xFFFFFFFFu;
    }
    __syncthreads();
    // exclusive scan hist[0..511]
    int run = 0;
    for (int cb = 0; cb < 512; cb += TPB) {
        int v = hist[cb + t];
        s[t] = v;
        __syncthreads();
        int x = v;
        for (int d = 1; d < TPB; d <<= 1) {
            int y = (t >= d) ? s[t - d] : 0;
            __syncthreads();
            x += y; s[t] = x;
            __syncthreads();
        }
        hist[cb + t] = run + (x - v);
        run += s[TPB - 1];
        __syncthreads();
    }
#pragma unroll
    for (int k = 0; k < EPT; ++k) {
        if (meta[k] != 0xFFFFFFFFu) {
            unsigned m = meta[k];
            int d = (int)(m >> 13);
            int lp = (int)(m & 0x1FFFu);
            unsigned p = (unsigned)src[base + k * TPB + t] | ((unsigned)(d & 255) << 17);
            sorted[hist[d >> 8] + lp] = p;
        }
    }
    __syncthreads();
    // 16-lane group per bucket-segment: contiguous LDS read, contiguous write
    int grp = t >> 4, ln = t & 15;
    for (int b = grp; b < NB; b += 16) {
        int ls = hist[b];               // LDS same-address broadcast
        int len = hist[b + 1] - ls;     // hist[NB] == n (bins >= NB are empty)
        int go = gbase[b];
        for (int k = ln; k < len; k += 16) pairs2[go + k] = sorted[ls + k];
    }
}

// ---- k_degree2: coalesced bucket read, count/scan, in-place sort, dinv ----
__global__ __launch_bounds__(TPB) void k_degree2(
    unsigned int* __restrict__ pairs2, const int* __restrict__ binBase,
    const int* __restrict__ binTotal, int* __restrict__ cnt,
    int* __restrict__ off, float* __restrict__ dinv,
    float* __restrict__ hs1, int N)
{
    __shared__ unsigned int pl[SLAB2];
    __shared__ int c[TPB], s[TPB], cur[TPB];
    int t = threadIdx.x, b = blockIdx.x;
    int base = binBase[b];
    int total = min(binTotal[b], SLAB2);
    c[t] = 0;
    __syncthreads();
    for (int i = t; i < total; i += TPB) pl[i] = pairs2[base + i];
    __syncthreads();
    for (int i = t; i < total; i += TPB) atomicAdd(&c[(pl[i] >> 17) & 255], 1);
    __syncthreads();
    int cv = c[t];
    s[t] = cv;
    __syncthreads();
    int x = cv;
    for (int d = 1; d < TPB; d <<= 1) {
        int y = (t >= d) ? s[t - d] : 0;
        __syncthreads();
        x += y; s[t] = x;
        __syncthreads();
    }
    int excl = x - cv;
    int v = (b << 8) + t;
    if (v < N) {
        cnt[v] = cv;
        off[v] = base + excl;
        float di = rsqrtf((float)(cv + 1));
        dinv[v] = di;
        float4 h = ((float4*)hs1)[v];           // raw h1 from k_node1
        ((float4*)hs1)[v] = make_float4(di * h.x, di * h.y, di * h.z, di * h.w);
    }
    cur[t] = excl;
    __syncthreads();
    // in-place counting sort: pairs2 run becomes dst-sorted src list (ssrc)
    for (int i = t; i < total; i += TPB) {
        unsigned p = pl[i];
        int pos = atomicAdd(&cur[(p >> 17) & 255], 1);
        pairs2[base + pos] = p & 0x1FFFFu;
    }
}

// ---- Layer-1 GEMM (128->4): hs1 = x@W1 (raw). Quad-per-node. ----
__global__ __launch_bounds__(TPB) void k_node1(
    const float* __restrict__ x, const float* __restrict__ W1,
    float* __restrict__ hs1, int n) {
    __shared__ float Ws[512];  // W1 [128][4] row-major
    for (int i = threadIdx.x; i < 512; i += TPB) Ws[i] = W1[i];
    __syncthreads();
    int t = blockIdx.x * TPB + threadIdx.x;
    int v = t >> 2, p = t & 3;
    if (v >= n) return;
    const float4* xr = (const float4*)(x + (size_t)v * 128);
    float a0 = 0.f, a1 = 0.f, a2 = 0.f, a3 = 0.f;
#pragma unroll
    for (int i = 0; i < 8; ++i) {
        int c = p + i * 4;
        float4 xx = xr[c];
        const float* w = &Ws[c * 16];
        a0 += xx.x * w[0] + xx.y * w[4] + xx.z * w[8]  + xx.w * w[12];
        a1 += xx.x * w[1] + xx.y * w[5] + xx.z * w[9]  + xx.w * w[13];
        a2 += xx.x * w[2] + xx.y * w[6] + xx.z * w[10] + xx.w * w[14];
        a3 += xx.x * w[3] + xx.y * w[7] + xx.z * w[11] + xx.w * w[15];
    }
    a0 += __shfl_xor(a0, 1); a0 += __shfl_xor(a0, 2);
    a1 += __shfl_xor(a1, 1); a1 += __shfl_xor(a1, 2);
    a2 += __shfl_xor(a2, 1); a2 += __shfl_xor(a2, 2);
    a3 += __shfl_xor(a3, 1); a3 += __shfl_xor(a3, 2);
    if (p == 0) ((float4*)hs1)[v] = make_float4(a0, a1, a2, a3);
}

// ---- gathers: 8 lanes per node over contiguous CSR segment ----
__global__ __launch_bounds__(TPB) void k_gather1(
    const int* __restrict__ off, const int* __restrict__ cnt,
    const int* __restrict__ ssrc, const float* __restrict__ hs1,
    const float* __restrict__ dinv, const float* __restrict__ b1,
    const float* __restrict__ W2, float* __restrict__ hs2, int n) {
    int t = blockIdx.x * TPB + threadIdx.x;
    int v = t >> 3, p = t & 7;
    if (v >= n) return;
    int base = off[v], c = cnt[v];
    float4 acc = make_float4(0.f, 0.f, 0.f, 0.f);
    for (int i = p; i < c; i += 8) {
        int s = ssrc[base + i];
        float4 h = ((const float4*)hs1)[s];
        acc.x += h.x; acc.y += h.y; acc.z += h.z; acc.w += h.w;
    }
    acc.x += __shfl_xor(acc.x, 1); acc.x += __shfl_xor(acc.x, 2); acc.x += __shfl_xor(acc.x, 4);
    acc.y += __shfl_xor(acc.y, 1); acc.y += __shfl_xor(acc.y, 2); acc.y += __shfl_xor(acc.y, 4);
    acc.z += __shfl_xor(acc.z, 1); acc.z += __shfl_xor(acc.z, 2); acc.z += __shfl_xor(acc.z, 4);
    acc.w += __shfl_xor(acc.w, 1); acc.w += __shfl_xor(acc.w, 2); acc.w += __shfl_xor(acc.w, 4);
    if (p == 0) {
        float4 hv = ((const float4*)hs1)[v];
        float di = dinv[v];
        float o0 = fmaxf(di * (acc.x + hv.x) + b1[0], 0.f);
        float o1 = fmaxf(di * (acc.y + hv.y) + b1[1], 0.f);
        float o2 = fmaxf(di * (acc.z + hv.z) + b1[2], 0.f);
        float o3 = fmaxf(di * (acc.w + hv.w) + b1[3], 0.f);
        float h0 = o0 * W2[0] + o1 * W2[2] + o2 * W2[4] + o3 * W2[6];
        float h1 = o0 * W2[1] + o1 * W2[3] + o2 * W2[5] + o3 * W2[7];
        ((float2*)hs2)[v] = make_float2(di * h0, di * h1);
    }
}

__global__ __launch_bounds__(TPB) void k_gather2(
    const int* __restrict__ off, const int* __restrict__ cnt,
    const int* __restrict__ ssrc, const float* __restrict__ hs2,
    const float* __restrict__ dinv, const float* __restrict__ b2,
    const float* __restrict__ W3, float* __restrict__ hs3, int n) {
    int t = blockIdx.x * TPB + threadIdx.x;
    int v = t >> 3, p = t & 7;
    if (v >= n) return;
    int base = off[v], c = cnt[v];
    float2 acc = make_float2(0.f, 0.f);
    for (int i = p; i < c; i += 8) {
        int s = ssrc[base + i];
        float2 h = ((const float2*)hs2)[s];
        acc.x += h.x; acc.y += h.y;
    }
    acc.x += __shfl_xor(acc.x, 1); acc.x += __shfl_xor(acc.x, 2); acc.x += __shfl_xor(acc.x, 4);
    acc.y += __shfl_xor(acc.y, 1); acc.y += __shfl_xor(acc.y, 2); acc.y += __shfl_xor(acc.y, 4);
    if (p == 0) {
        float2 hv = ((const float2*)hs2)[v];
        float di = dinv[v];
        float o0 = fmaxf(di * (acc.x + hv.x) + b2[0], 0.f);
        float o1 = fmaxf(di * (acc.y + hv.y) + b2[1], 0.f);
        float h3 = o0 * W3[0] + o1 * W3[1];
        hs3[v] = di * h3;
    }
}

__global__ __launch_bounds__(TPB) void k_gather3(
    const int* __restrict__ off, const int* __restrict__ cnt,
    const int* __restrict__ ssrc, const float* __restrict__ hs3,
    const float* __restrict__ dinv, const float* __restrict__ b3,
    float* __restrict__ out, int n) {
    int t = blockIdx.x * TPB + threadIdx.x;
    int v = t >> 3, p = t & 7;
    if (v >= n) return;
    int base = off[v], c = cnt[v];
    float acc = 0.f;
    for (int i = p; i < c; i += 8) acc += hs3[ssrc[base + i]];
    acc += __shfl_xor(acc, 1); acc += __shfl_xor(acc, 2); acc += __shfl_xor(acc, 4);
    if (p == 0) {
        float di = dinv[v];
        float agg = di * (acc + hs3[v]) + b3[0];
        out[v] = 1.0f / (1.0f + __expf(-agg));
    }
}

extern "C" void kernel_launch(void* const* d_in, const int* in_sizes, int n_in,
                              void* d_out, int out_size, void* d_ws, size_t ws_size,
                              hipStream_t stream) {
    const float* x  = (const float*)d_in[0];
    const int* ei   = (const int*)d_in[1];
    const float* W1 = (const float*)d_in[2];
    const float* b1 = (const float*)d_in[3];
    const float* W2 = (const float*)d_in[4];
    const float* b2 = (const float*)d_in[5];
    const float* W3 = (const float*)d_in[6];
    const float* b3 = (const float*)d_in[7];
    float* out = (float*)d_out;

    const int N = in_sizes[0] / 128;
    const int E = in_sizes[1] / 2;
    const int* src = ei;
    const int* dst = ei + E;

    const int NS = (E + CHUNK - 1) / CHUNK;   // 782 chunks
    const int NB = (N + 255) >> 8;            // 391 buckets

    // ws carve (~18 MB)
    char* w = (char*)d_ws;
    auto carve = [&](size_t bytes) { char* p = w; w += (bytes + 15) & ~(size_t)15; return p; };
    int* histT           = (int*)carve((size_t)NB * NS * 4);
    int* binTotal        = (int*)carve((size_t)NB * 4);
    int* binBase         = (int*)carve((size_t)NB * 4);
    unsigned int* pairs2 = (unsigned int*)carve((size_t)E * 4);  // -> ssrc
    int* cnt             = (int*)carve((size_t)N * 4);
    int* off             = (int*)carve((size_t)N * 4);
    float* dinv          = (float*)carve((size_t)N * 4);
    float* hs1           = (float*)carve((size_t)N * 16);
    float* hs2           = (float*)carve((size_t)N * 8);
    float* hs3           = (float*)carve((size_t)N * 4);

    const int nbN4 = (4 * N + TPB - 1) / TPB;
    const int nbN8 = (8 * N + TPB - 1) / TPB;

    k_hist       <<<NS, TPB, 0, stream>>>(dst, histT, NS, NB, E);
    k_scanA      <<<NB, TPB, 0, stream>>>(histT, binTotal, NS);
    k_scanB      <<<1, 512, 0, stream>>>(binTotal, binBase, NB);
    k_node1      <<<nbN4, TPB, 0, stream>>>(x, W1, hs1, N);
    k_sortscatter<<<NS, TPB, 0, stream>>>(src, dst, histT, binBase, pairs2, NS, NB, E);
    k_degree2    <<<NB, TPB, 0, stream>>>(pairs2, binBase, binTotal, cnt, off, dinv, hs1, N);
    k_gather1    <<<nbN8, TPB, 0, stream>>>(off, cnt, (const int*)pairs2, hs1, dinv, b1, W2, hs2, N);
    k_gather2    <<<nbN8, TPB, 0, stream>>>(off, cnt, (const int*)pairs2, hs2, dinv, b2, W3, hs3, N);
    k_gather3    <<<nbN8, TPB, 0, stream>>>(off, cnt, (const int*)pairs2, hs3, dinv, b3, out, N);
}

// Round 7
// 227.184 us; speedup vs baseline: 1.0231x; 1.0231x over previous
//
#include <hip/hip_runtime.h>
#include <hip/hip_bf16.h>
#include <math.h>

// GCN 3-layer inference. N=100000, E=3200000, feats 128->4->2->1.
// R7: minimal-pass MSB-radix CSR build. Raw edges read ONCE, one LDS sort.
//  k_part   : LDS counting-sort chunk by bucket(dst>>8) -> sorted slab
//             (coalesced) + lstart[chunk][bin] local offsets (coalesced)
//             + cntT[bin][chunk] counts (transposed for coalesced scanA).
//  k_scanA  : per-bin coalesced scan of cntT over chunks -> dest offsets,
//             binTotal.  k_scanB: scan binTotal -> binBase.
//  k_place  : chunk -> LDS, 8-lane groups copy bucket segments to final
//             bucket-contiguous pairs2 positions. Pure copy.
//  k_degree2: per bucket: coalesced read, per-node count+scan -> cnt/off/
//             dinv, scale hs1*=dinv, in-place counting sort -> ssrc.
//  k_node1  : 128->4 GEMM (raw h1), quad-per-node.
//  k_gather*: 8 lanes/node over contiguous CSR segment, fused epilogues.
// Edge pack: p = src | (dst&255)<<17  (src < 2^17).

#define TPB 256
#define CHUNK 4096
#define EPT (CHUNK / TPB)
#define SLAB2 9216          // per-bucket capacity (mean 8192, +11 sigma)

// ---- k_part: one LDS counting sort per 4096-edge chunk ----
__global__ __launch_bounds__(TPB) void k_part(
    const int* __restrict__ src, const int* __restrict__ dst,
    unsigned int* __restrict__ slab, int* __restrict__ lstart,
    int* __restrict__ cntT, int NS, int NB, int NBP, int E)
{
    __shared__ int hist[512];
    __shared__ int s[TPB];
    __shared__ unsigned int sorted[CHUNK];
    int t = threadIdx.x, blk = blockIdx.x;
    int base = blk * CHUNK;
    int n = min(CHUNK, E - base);
    hist[t] = 0; hist[t + 256] = 0;
    __syncthreads();
    unsigned int meta[EPT];   // d<<13 | lp  (lp < 4096)
#pragma unroll
    for (int k = 0; k < EPT; ++k) {
        int li = k * TPB + t;
        if (li < n) {
            int d = dst[base + li];
            int lp = atomicAdd(&hist[d >> 8], 1);
            meta[k] = ((unsigned)d << 13) | (unsigned)lp;
        } else meta[k] = 0xFFFFFFFFu;
    }
    __syncthreads();
    // counts out (transposed) BEFORE scan overwrites hist
    for (int i = t; i < NB; i += TPB) cntT[(size_t)i * NS + blk] = hist[i];
    __syncthreads();
    // exclusive scan hist[0..511]
    int run = 0;
    for (int cb = 0; cb < 512; cb += TPB) {
        int v = hist[cb + t];
        s[t] = v;
        __syncthreads();
        int x = v;
        for (int d = 1; d < TPB; d <<= 1) {
            int y = (t >= d) ? s[t - d] : 0;
            __syncthreads();
            x += y; s[t] = x;
            __syncthreads();
        }
        hist[cb + t] = run + (x - v);
        run += s[TPB - 1];
        __syncthreads();
    }
#pragma unroll
    for (int k = 0; k < EPT; ++k) {
        if (meta[k] != 0xFFFFFFFFu) {
            unsigned m = meta[k];
            int d = (int)(m >> 13);
            int lp = (int)(m & 0x1FFFu);
            unsigned p = (unsigned)src[base + k * TPB + t] | ((unsigned)(d & 255) << 17);
            sorted[hist[d >> 8] + lp] = p;
        }
    }
    __syncthreads();
    const uint4* s4 = (const uint4*)sorted;
    uint4* g4 = (uint4*)(slab + (size_t)base);
    for (int i = t; i < CHUNK / 4; i += TPB) g4[i] = s4[i];
    for (int i = t; i < NBP; i += TPB)
        lstart[(size_t)blk * NBP + i] = (i < NB) ? hist[i] : n;
}

// ---- k_scanA: per bin, coalesced exclusive scan of cntT over chunks ----
__global__ __launch_bounds__(TPB) void k_scanA(int* __restrict__ cntT,
                                               int* __restrict__ binTotal, int NS) {
    __shared__ int s[TPB];
    int* row = cntT + (size_t)blockIdx.x * NS;
    int t = threadIdx.x;
    int run = 0;
    for (int base = 0; base < NS; base += TPB) {
        int i = base + t;
        int v = (i < NS) ? row[i] : 0;
        s[t] = v;
        __syncthreads();
        int x = v;
        for (int d = 1; d < TPB; d <<= 1) {
            int y = (t >= d) ? s[t - d] : 0;
            __syncthreads();
            x += y; s[t] = x;
            __syncthreads();
        }
        if (i < NS) row[i] = run + (x - v);
        run += s[TPB - 1];
        __syncthreads();
    }
    if (t == 0) binTotal[blockIdx.x] = run;
}

// ---- k_scanB: exclusive scan binTotal -> binBase ----
__global__ __launch_bounds__(512) void k_scanB(const int* __restrict__ binTotal,
                                               int* __restrict__ binBase, int NB) {
    __shared__ int s[512];
    int t = threadIdx.x;
    int v = (t < NB) ? binTotal[t] : 0;
    s[t] = v;
    __syncthreads();
    int x = v;
    for (int d = 1; d < 512; d <<= 1) {
        int y = (t >= d) ? s[t - d] : 0;
        __syncthreads();
        x += y; s[t] = x;
        __syncthreads();
    }
    if (t < NB) binBase[t] = x - v;
}

// ---- k_place: copy sorted chunk segments to bucket-contiguous pairs2 ----
__global__ __launch_bounds__(TPB) void k_place(
    const unsigned int* __restrict__ slab, const int* __restrict__ lstart,
    const int* __restrict__ cntT /* holds dest offsets */,
    const int* __restrict__ binBase, unsigned int* __restrict__ pairs2,
    int NS, int NB, int NBP)
{
    __shared__ unsigned int ch[CHUNK];
    __shared__ int lls[512];
    __shared__ int ddo[512];
    int t = threadIdx.x, blk = blockIdx.x;
    const uint4* g4 = (const uint4*)(slab + (size_t)blk * CHUNK);
    uint4* c4 = (uint4*)ch;
    for (int i = t; i < CHUNK / 4; i += TPB) c4[i] = g4[i];
    for (int i = t; i < NBP; i += TPB) lls[i] = lstart[(size_t)blk * NBP + i];
    for (int i = t; i < NB; i += TPB)
        ddo[i] = binBase[i] + cntT[(size_t)i * NS + blk];
    __syncthreads();
    int grp = t >> 3, ln = t & 7;   // 32 groups x 8 lanes
    for (int b = grp; b < NB; b += 32) {
        int ls = lls[b];
        int len = lls[b + 1] - ls;
        int go = ddo[b];
        for (int k = ln; k < len; k += 8) pairs2[go + k] = ch[ls + k];
    }
}

// ---- k_degree2: count/scan -> cnt/off/dinv, scale hs1, in-place sort ----
__global__ __launch_bounds__(TPB) void k_degree2(
    unsigned int* __restrict__ pairs2, const int* __restrict__ binBase,
    const int* __restrict__ binTotal, int* __restrict__ cnt,
    int* __restrict__ off, float* __restrict__ dinv,
    float* __restrict__ hs1, int N)
{
    __shared__ unsigned int pl[SLAB2];
    __shared__ int c[TPB], s[TPB], cur[TPB];
    int t = threadIdx.x, b = blockIdx.x;
    int base = binBase[b];
    int total = min(binTotal[b], SLAB2);
    c[t] = 0;
    __syncthreads();
    for (int i = t; i < total; i += TPB) pl[i] = pairs2[base + i];
    __syncthreads();
    for (int i = t; i < total; i += TPB) atomicAdd(&c[(pl[i] >> 17) & 255], 1);
    __syncthreads();
    int cv = c[t];
    s[t] = cv;
    __syncthreads();
    int x = cv;
    for (int d = 1; d < TPB; d <<= 1) {
        int y = (t >= d) ? s[t - d] : 0;
        __syncthreads();
        x += y; s[t] = x;
        __syncthreads();
    }
    int excl = x - cv;
    int v = (b << 8) + t;
    if (v < N) {
        cnt[v] = cv;
        off[v] = base + excl;
        float di = rsqrtf((float)(cv + 1));
        dinv[v] = di;
        float4 h = ((float4*)hs1)[v];
        ((float4*)hs1)[v] = make_float4(di * h.x, di * h.y, di * h.z, di * h.w);
    }
    cur[t] = excl;
    __syncthreads();
    for (int i = t; i < total; i += TPB) {
        unsigned p = pl[i];
        int pos = atomicAdd(&cur[(p >> 17) & 255], 1);
        pairs2[base + pos] = p & 0x1FFFFu;
    }
}

// ---- Layer-1 GEMM (128->4): hs1 = x@W1 (raw). Quad-per-node. ----
__global__ __launch_bounds__(TPB) void k_node1(
    const float* __restrict__ x, const float* __restrict__ W1,
    float* __restrict__ hs1, int n) {
    __shared__ float Ws[512];  // W1 [128][4] row-major
    for (int i = threadIdx.x; i < 512; i += TPB) Ws[i] = W1[i];
    __syncthreads();
    int t = blockIdx.x * TPB + threadIdx.x;
    int v = t >> 2, p = t & 3;
    if (v >= n) return;
    const float4* xr = (const float4*)(x + (size_t)v * 128);
    float a0 = 0.f, a1 = 0.f, a2 = 0.f, a3 = 0.f;
#pragma unroll
    for (int i = 0; i < 8; ++i) {
        int c = p + i * 4;
        float4 xx = xr[c];
        const float* w = &Ws[c * 16];
        a0 += xx.x * w[0] + xx.y * w[4] + xx.z * w[8]  + xx.w * w[12];
        a1 += xx.x * w[1] + xx.y * w[5] + xx.z * w[9]  + xx.w * w[13];
        a2 += xx.x * w[2] + xx.y * w[6] + xx.z * w[10] + xx.w * w[14];
        a3 += xx.x * w[3] + xx.y * w[7] + xx.z * w[11] + xx.w * w[15];
    }
    a0 += __shfl_xor(a0, 1); a0 += __shfl_xor(a0, 2);
    a1 += __shfl_xor(a1, 1); a1 += __shfl_xor(a1, 2);
    a2 += __shfl_xor(a2, 1); a2 += __shfl_xor(a2, 2);
    a3 += __shfl_xor(a3, 1); a3 += __shfl_xor(a3, 2);
    if (p == 0) ((float4*)hs1)[v] = make_float4(a0, a1, a2, a3);
}

// ---- gathers: 8 lanes per node over contiguous CSR segment ----
__global__ __launch_bounds__(TPB) void k_gather1(
    const int* __restrict__ off, const int* __restrict__ cnt,
    const int* __restrict__ ssrc, const float* __restrict__ hs1,
    const float* __restrict__ dinv, const float* __restrict__ b1,
    const float* __restrict__ W2, float* __restrict__ hs2, int n) {
    int t = blockIdx.x * TPB + threadIdx.x;
    int v = t >> 3, p = t & 7;
    if (v >= n) return;
    int base = off[v], c = cnt[v];
    float4 acc = make_float4(0.f, 0.f, 0.f, 0.f);
    for (int i = p; i < c; i += 8) {
        int s = ssrc[base + i];
        float4 h = ((const float4*)hs1)[s];
        acc.x += h.x; acc.y += h.y; acc.z += h.z; acc.w += h.w;
    }
    acc.x += __shfl_xor(acc.x, 1); acc.x += __shfl_xor(acc.x, 2); acc.x += __shfl_xor(acc.x, 4);
    acc.y += __shfl_xor(acc.y, 1); acc.y += __shfl_xor(acc.y, 2); acc.y += __shfl_xor(acc.y, 4);
    acc.z += __shfl_xor(acc.z, 1); acc.z += __shfl_xor(acc.z, 2); acc.z += __shfl_xor(acc.z, 4);
    acc.w += __shfl_xor(acc.w, 1); acc.w += __shfl_xor(acc.w, 2); acc.w += __shfl_xor(acc.w, 4);
    if (p == 0) {
        float4 hv = ((const float4*)hs1)[v];
        float di = dinv[v];
        float o0 = fmaxf(di * (acc.x + hv.x) + b1[0], 0.f);
        float o1 = fmaxf(di * (acc.y + hv.y) + b1[1], 0.f);
        float o2 = fmaxf(di * (acc.z + hv.z) + b1[2], 0.f);
        float o3 = fmaxf(di * (acc.w + hv.w) + b1[3], 0.f);
        float h0 = o0 * W2[0] + o1 * W2[2] + o2 * W2[4] + o3 * W2[6];
        float h1 = o0 * W2[1] + o1 * W2[3] + o2 * W2[5] + o3 * W2[7];
        ((float2*)hs2)[v] = make_float2(di * h0, di * h1);
    }
}

__global__ __launch_bounds__(TPB) void k_gather2(
    const int* __restrict__ off, const int* __restrict__ cnt,
    const int* __restrict__ ssrc, const float* __restrict__ hs2,
    const float* __restrict__ dinv, const float* __restrict__ b2,
    const float* __restrict__ W3, float* __restrict__ hs3, int n) {
    int t = blockIdx.x * TPB + threadIdx.x;
    int v = t >> 3, p = t & 7;
    if (v >= n) return;
    int base = off[v], c = cnt[v];
    float2 acc = make_float2(0.f, 0.f);
    for (int i = p; i < c; i += 8) {
        int s = ssrc[base + i];
        float2 h = ((const float2*)hs2)[s];
        acc.x += h.x; acc.y += h.y;
    }
    acc.x += __shfl_xor(acc.x, 1); acc.x += __shfl_xor(acc.x, 2); acc.x += __shfl_xor(acc.x, 4);
    acc.y += __shfl_xor(acc.y, 1); acc.y += __shfl_xor(acc.y, 2); acc.y += __shfl_xor(acc.y, 4);
    if (p == 0) {
        float2 hv = ((const float2*)hs2)[v];
        float di = dinv[v];
        float o0 = fmaxf(di * (acc.x + hv.x) + b2[0], 0.f);
        float o1 = fmaxf(di * (acc.y + hv.y) + b2[1], 0.f);
        float h3 = o0 * W3[0] + o1 * W3[1];
        hs3[v] = di * h3;
    }
}

__global__ __launch_bounds__(TPB) void k_gather3(
    const int* __restrict__ off, const int* __restrict__ cnt,
    const int* __restrict__ ssrc, const float* __restrict__ hs3,
    const float* __restrict__ dinv, const float* __restrict__ b3,
    float* __restrict__ out, int n) {
    int t = blockIdx.x * TPB + threadIdx.x;
    int v = t >> 3, p = t & 7;
    if (v >= n) return;
    int base = off[v], c = cnt[v];
    float acc = 0.f;
    for (int i = p; i < c; i += 8) acc += hs3[ssrc[base + i]];
    acc += __shfl_xor(acc, 1); acc += __shfl_xor(acc, 2); acc += __shfl_xor(acc, 4);
    if (p == 0) {
        float di = dinv[v];
        float agg = di * (acc + hs3[v]) + b3[0];
        out[v] = 1.0f / (1.0f + __expf(-agg));
    }
}

extern "C" void kernel_launch(void* const* d_in, const int* in_sizes, int n_in,
                              void* d_out, int out_size, void* d_ws, size_t ws_size,
                              hipStream_t stream) {
    const float* x  = (const float*)d_in[0];
    const int* ei   = (const int*)d_in[1];
    const float* W1 = (const float*)d_in[2];
    const float* b1 = (const float*)d_in[3];
    const float* W2 = (const float*)d_in[4];
    const float* b2 = (const float*)d_in[5];
    const float* W3 = (const float*)d_in[6];
    const float* b3 = (const float*)d_in[7];
    float* out = (float*)d_out;

    const int N = in_sizes[0] / 128;
    const int E = in_sizes[1] / 2;
    const int* src = ei;
    const int* dst = ei + E;

    const int NS  = (E + CHUNK - 1) / CHUNK;  // 782 chunks
    const int NB  = (N + 255) >> 8;           // 391 buckets
    const int NBP = NB + 1;

    // ws carve (~33 MB)
    char* w = (char*)d_ws;
    auto carve = [&](size_t bytes) { char* p = w; w += (bytes + 15) & ~(size_t)15; return p; };
    unsigned int* slab   = (unsigned int*)carve((size_t)NS * CHUNK * 4);
    int* lstart          = (int*)carve((size_t)NS * NBP * 4);
    int* cntT            = (int*)carve((size_t)NB * NS * 4);
    int* binTotal        = (int*)carve((size_t)NB * 4);
    int* binBase         = (int*)carve((size_t)NB * 4);
    unsigned int* pairs2 = (unsigned int*)carve((size_t)E * 4);  // -> ssrc
    int* cnt             = (int*)carve((size_t)N * 4);
    int* off             = (int*)carve((size_t)N * 4);
    float* dinv          = (float*)carve((size_t)N * 4);
    float* hs1           = (float*)carve((size_t)N * 16);
    float* hs2           = (float*)carve((size_t)N * 8);
    float* hs3           = (float*)carve((size_t)N * 4);

    const int nbN4 = (4 * N + TPB - 1) / TPB;
    const int nbN8 = (8 * N + TPB - 1) / TPB;

    k_part   <<<NS, TPB, 0, stream>>>(src, dst, slab, lstart, cntT, NS, NB, NBP, E);
    k_scanA  <<<NB, TPB, 0, stream>>>(cntT, binTotal, NS);
    k_scanB  <<<1, 512, 0, stream>>>(binTotal, binBase, NB);
    k_node1  <<<nbN4, TPB, 0, stream>>>(x, W1, hs1, N);
    k_place  <<<NS, TPB, 0, stream>>>(slab, lstart, cntT, binBase, pairs2, NS, NB, NBP);
    k_degree2<<<NB, TPB, 0, stream>>>(pairs2, binBase, binTotal, cnt, off, dinv, hs1, N);
    k_gather1<<<nbN8, TPB, 0, stream>>>(off, cnt, (const int*)pairs2, hs1, dinv, b1, W2, hs2, N);
    k_gather2<<<nbN8, TPB, 0, stream>>>(off, cnt, (const int*)pairs2, hs2, dinv, b2, W3, hs3, N);
    k_gather3<<<nbN8, TPB, 0, stream>>>(off, cnt, (const int*)pairs2, hs3, dinv, b3, out, N);
}

// Round 8
// 224.097 us; speedup vs baseline: 1.0372x; 1.0138x over previous
//
#include <hip/hip_runtime.h>
#include <hip/hip_bf16.h>
#include <math.h>

// GCN 3-layer inference. N=100000, E=3200000, feats 128->4->2->1.
// R8: 2-pass CSR build with fixed per-bucket regions + per-(chunk,bin)
// device-atomic allocation (306k atomics ~ 13us at measured 24G/s, vs
// R7's 4 global round-trips of the edge payload + 5 build passes).
//  k_node1      : 128->4 GEMM (raw h1), quad-per-node; block 0 zeros cursor.
//  k_partscatter: LDS counting-sort 4096-edge chunk by bucket(dst>>8),
//                 atomicAdd cursor[bin] len -> segment base in the bucket's
//                 fixed SLAB2 region, 16-lane-group contiguous copy.
//  k_degree2    : per bucket: coalesced read, per-node count+scan ->
//                 cnt/off/dinv, scale hs1*=dinv, in-place sort -> ssrc.
//  k_gather1/2/3: 8 lanes/node over contiguous CSR segment, fused epilogues.
// Edge pack: p = src | (dst&255)<<17  (src < 2^17).

#define TPB 256
#define CHUNK 4096
#define EPT (CHUNK / TPB)
#define SLAB2 9216          // per-bucket capacity (mean 8184, +11 sigma)

// ---- Layer-1 GEMM (128->4): hs1 = x@W1 (raw). Also zero cursor. ----
__global__ __launch_bounds__(TPB) void k_node1(
    const float* __restrict__ x, const float* __restrict__ W1,
    float* __restrict__ hs1, int* __restrict__ cursor, int NB, int n) {
    __shared__ float Ws[512];  // W1 [128][4] row-major
    if (blockIdx.x == 0)
        for (int i = threadIdx.x; i < NB; i += TPB) cursor[i] = 0;
    for (int i = threadIdx.x; i < 512; i += TPB) Ws[i] = W1[i];
    __syncthreads();
    int t = blockIdx.x * TPB + threadIdx.x;
    int v = t >> 2, p = t & 3;
    if (v >= n) return;
    const float4* xr = (const float4*)(x + (size_t)v * 128);
    float a0 = 0.f, a1 = 0.f, a2 = 0.f, a3 = 0.f;
#pragma unroll
    for (int i = 0; i < 8; ++i) {
        int c = p + i * 4;
        float4 xx = xr[c];
        const float* w = &Ws[c * 16];
        a0 += xx.x * w[0] + xx.y * w[4] + xx.z * w[8]  + xx.w * w[12];
        a1 += xx.x * w[1] + xx.y * w[5] + xx.z * w[9]  + xx.w * w[13];
        a2 += xx.x * w[2] + xx.y * w[6] + xx.z * w[10] + xx.w * w[14];
        a3 += xx.x * w[3] + xx.y * w[7] + xx.z * w[11] + xx.w * w[15];
    }
    a0 += __shfl_xor(a0, 1); a0 += __shfl_xor(a0, 2);
    a1 += __shfl_xor(a1, 1); a1 += __shfl_xor(a1, 2);
    a2 += __shfl_xor(a2, 1); a2 += __shfl_xor(a2, 2);
    a3 += __shfl_xor(a3, 1); a3 += __shfl_xor(a3, 2);
    if (p == 0) ((float4*)hs1)[v] = make_float4(a0, a1, a2, a3);
}

// ---- k_partscatter: LDS sort + atomic region alloc + direct placement ----
__global__ __launch_bounds__(TPB) void k_partscatter(
    const int* __restrict__ src, const int* __restrict__ dst,
    int* __restrict__ cursor, unsigned int* __restrict__ pairs2,
    int NB, int E)
{
    __shared__ int hist[512];
    __shared__ int s[TPB];
    __shared__ int gstart[512];
    __shared__ unsigned int sorted[CHUNK];
    int t = threadIdx.x, blk = blockIdx.x;
    int base = blk * CHUNK;
    int n = min(CHUNK, E - base);
    hist[t] = 0; hist[t + 256] = 0;
    __syncthreads();
    unsigned int meta[EPT];   // d<<13 | lp  (lp < 4096)
#pragma unroll
    for (int k = 0; k < EPT; ++k) {
        int li = k * TPB + t;
        if (li < n) {
            int d = dst[base + li];
            int lp = atomicAdd(&hist[d >> 8], 1);
            meta[k] = ((unsigned)d << 13) | (unsigned)lp;
        } else meta[k] = 0xFFFFFFFFu;
    }
    __syncthreads();
    // exclusive scan hist[0..511] -> local segment starts
    int run = 0;
    for (int cb = 0; cb < 512; cb += TPB) {
        int v = hist[cb + t];
        s[t] = v;
        __syncthreads();
        int x = v;
        for (int d = 1; d < TPB; d <<= 1) {
            int y = (t >= d) ? s[t - d] : 0;
            __syncthreads();
            x += y; s[t] = x;
            __syncthreads();
        }
        hist[cb + t] = run + (x - v);
        run += s[TPB - 1];
        __syncthreads();
    }
    // scatter into LDS sorted order
#pragma unroll
    for (int k = 0; k < EPT; ++k) {
        if (meta[k] != 0xFFFFFFFFu) {
            unsigned m = meta[k];
            int d = (int)(m >> 13);
            int lp = (int)(m & 0x1FFFu);
            unsigned p = (unsigned)src[base + k * TPB + t] | ((unsigned)(d & 255) << 17);
            sorted[hist[d >> 8] + lp] = p;
        }
    }
    __syncthreads();
    // per-bin global region allocation (device atomic, one per non-empty bin)
    for (int b = t; b < NB; b += TPB) {
        int len = hist[b + 1] - hist[b];   // hist[NB]==n (bins>=NB empty)
        gstart[b] = (len > 0) ? atomicAdd(&cursor[b], len) : 0;
    }
    __syncthreads();
    // 16-lane group per segment: contiguous copy into bucket's fixed region
    int grp = t >> 4, ln = t & 15;
    for (int b = grp; b < NB; b += 16) {
        int ls = hist[b];
        int len = hist[b + 1] - ls;
        int gs = gstart[b];
        unsigned int* dp = pairs2 + (size_t)b * SLAB2;
        int lim = min(gs + len, SLAB2);    // overflow guard (prob ~0)
        for (int k = gs + ln; k < lim; k += 16) dp[k] = sorted[ls + (k - gs)];
    }
}

// ---- k_degree2: count/scan -> cnt/off/dinv, scale hs1, in-place sort ----
__global__ __launch_bounds__(TPB) void k_degree2(
    unsigned int* __restrict__ pairs2, const int* __restrict__ cursor,
    int* __restrict__ cnt, int* __restrict__ off, float* __restrict__ dinv,
    float* __restrict__ hs1, int N)
{
    __shared__ unsigned int pl[SLAB2];
    __shared__ int c[TPB], s[TPB], cur[TPB];
    int t = threadIdx.x, b = blockIdx.x;
    int base = b * SLAB2;
    int total = min(cursor[b], SLAB2);
    c[t] = 0;
    __syncthreads();
    for (int i = t; i < total; i += TPB) pl[i] = pairs2[base + i];
    __syncthreads();
    for (int i = t; i < total; i += TPB) atomicAdd(&c[(pl[i] >> 17) & 255], 1);
    __syncthreads();
    int cv = c[t];
    s[t] = cv;
    __syncthreads();
    int x = cv;
    for (int d = 1; d < TPB; d <<= 1) {
        int y = (t >= d) ? s[t - d] : 0;
        __syncthreads();
        x += y; s[t] = x;
        __syncthreads();
    }
    int excl = x - cv;
    int v = (b << 8) + t;
    if (v < N) {
        cnt[v] = cv;
        off[v] = base + excl;
        float di = rsqrtf((float)(cv + 1));
        dinv[v] = di;
        float4 h = ((float4*)hs1)[v];
        ((float4*)hs1)[v] = make_float4(di * h.x, di * h.y, di * h.z, di * h.w);
    }
    cur[t] = excl;
    __syncthreads();
    // in-place counting sort: bucket region becomes dst-sorted src list
    for (int i = t; i < total; i += TPB) {
        unsigned p = pl[i];
        int pos = atomicAdd(&cur[(p >> 17) & 255], 1);
        pairs2[base + pos] = p & 0x1FFFFu;
    }
}

// ---- gathers: 8 lanes per node over contiguous CSR segment ----
__global__ __launch_bounds__(TPB) void k_gather1(
    const int* __restrict__ off, const int* __restrict__ cnt,
    const int* __restrict__ ssrc, const float* __restrict__ hs1,
    const float* __restrict__ dinv, const float* __restrict__ b1,
    const float* __restrict__ W2, float* __restrict__ hs2, int n) {
    int t = blockIdx.x * TPB + threadIdx.x;
    int v = t >> 3, p = t & 7;
    if (v >= n) return;
    int base = off[v], c = cnt[v];
    float4 acc = make_float4(0.f, 0.f, 0.f, 0.f);
    for (int i = p; i < c; i += 8) {
        int s = ssrc[base + i];
        float4 h = ((const float4*)hs1)[s];
        acc.x += h.x; acc.y += h.y; acc.z += h.z; acc.w += h.w;
    }
    acc.x += __shfl_xor(acc.x, 1); acc.x += __shfl_xor(acc.x, 2); acc.x += __shfl_xor(acc.x, 4);
    acc.y += __shfl_xor(acc.y, 1); acc.y += __shfl_xor(acc.y, 2); acc.y += __shfl_xor(acc.y, 4);
    acc.z += __shfl_xor(acc.z, 1); acc.z += __shfl_xor(acc.z, 2); acc.z += __shfl_xor(acc.z, 4);
    acc.w += __shfl_xor(acc.w, 1); acc.w += __shfl_xor(acc.w, 2); acc.w += __shfl_xor(acc.w, 4);
    if (p == 0) {
        float4 hv = ((const float4*)hs1)[v];
        float di = dinv[v];
        float o0 = fmaxf(di * (acc.x + hv.x) + b1[0], 0.f);
        float o1 = fmaxf(di * (acc.y + hv.y) + b1[1], 0.f);
        float o2 = fmaxf(di * (acc.z + hv.z) + b1[2], 0.f);
        float o3 = fmaxf(di * (acc.w + hv.w) + b1[3], 0.f);
        float h0 = o0 * W2[0] + o1 * W2[2] + o2 * W2[4] + o3 * W2[6];
        float h1 = o0 * W2[1] + o1 * W2[3] + o2 * W2[5] + o3 * W2[7];
        ((float2*)hs2)[v] = make_float2(di * h0, di * h1);
    }
}

__global__ __launch_bounds__(TPB) void k_gather2(
    const int* __restrict__ off, const int* __restrict__ cnt,
    const int* __restrict__ ssrc, const float* __restrict__ hs2,
    const float* __restrict__ dinv, const float* __restrict__ b2,
    const float* __restrict__ W3, float* __restrict__ hs3, int n) {
    int t = blockIdx.x * TPB + threadIdx.x;
    int v = t >> 3, p = t & 7;
    if (v >= n) return;
    int base = off[v], c = cnt[v];
    float2 acc = make_float2(0.f, 0.f);
    for (int i = p; i < c; i += 8) {
        int s = ssrc[base + i];
        float2 h = ((const float2*)hs2)[s];
        acc.x += h.x; acc.y += h.y;
    }
    acc.x += __shfl_xor(acc.x, 1); acc.x += __shfl_xor(acc.x, 2); acc.x += __shfl_xor(acc.x, 4);
    acc.y += __shfl_xor(acc.y, 1); acc.y += __shfl_xor(acc.y, 2); acc.y += __shfl_xor(acc.y, 4);
    if (p == 0) {
        float2 hv = ((const float2*)hs2)[v];
        float di = dinv[v];
        float o0 = fmaxf(di * (acc.x + hv.x) + b2[0], 0.f);
        float o1 = fmaxf(di * (acc.y + hv.y) + b2[1], 0.f);
        float h3 = o0 * W3[0] + o1 * W3[1];
        hs3[v] = di * h3;
    }
}

__global__ __launch_bounds__(TPB) void k_gather3(
    const int* __restrict__ off, const int* __restrict__ cnt,
    const int* __restrict__ ssrc, const float* __restrict__ hs3,
    const float* __restrict__ dinv, const float* __restrict__ b3,
    float* __restrict__ out, int n) {
    int t = blockIdx.x * TPB + threadIdx.x;
    int v = t >> 3, p = t & 7;
    if (v >= n) return;
    int base = off[v], c = cnt[v];
    float acc = 0.f;
    for (int i = p; i < c; i += 8) acc += hs3[ssrc[base + i]];
    acc += __shfl_xor(acc, 1); acc += __shfl_xor(acc, 2); acc += __shfl_xor(acc, 4);
    if (p == 0) {
        float di = dinv[v];
        float agg = di * (acc + hs3[v]) + b3[0];
        out[v] = 1.0f / (1.0f + __expf(-agg));
    }
}

extern "C" void kernel_launch(void* const* d_in, const int* in_sizes, int n_in,
                              void* d_out, int out_size, void* d_ws, size_t ws_size,
                              hipStream_t stream) {
    const float* x  = (const float*)d_in[0];
    const int* ei   = (const int*)d_in[1];
    const float* W1 = (const float*)d_in[2];
    const float* b1 = (const float*)d_in[3];
    const float* W2 = (const float*)d_in[4];
    const float* b2 = (const float*)d_in[5];
    const float* W3 = (const float*)d_in[6];
    const float* b3 = (const float*)d_in[7];
    float* out = (float*)d_out;

    const int N = in_sizes[0] / 128;
    const int E = in_sizes[1] / 2;
    const int* src = ei;
    const int* dst = ei + E;

    const int NS = (E + CHUNK - 1) / CHUNK;   // 782 chunks
    const int NB = (N + 255) >> 8;            // 391 buckets

    // ws carve (~18.6 MB)
    char* w = (char*)d_ws;
    auto carve = [&](size_t bytes) { char* p = w; w += (bytes + 15) & ~(size_t)15; return p; };
    unsigned int* pairs2 = (unsigned int*)carve((size_t)NB * SLAB2 * 4);  // -> ssrc
    int* cursor          = (int*)carve((size_t)NB * 4);
    int* cnt             = (int*)carve((size_t)N * 4);
    int* off             = (int*)carve((size_t)N * 4);
    float* dinv          = (float*)carve((size_t)N * 4);
    float* hs1           = (float*)carve((size_t)N * 16);
    float* hs2           = (float*)carve((size_t)N * 8);
    float* hs3           = (float*)carve((size_t)N * 4);

    const int nbN4 = (4 * N + TPB - 1) / TPB;
    const int nbN8 = (8 * N + TPB - 1) / TPB;

    k_node1      <<<nbN4, TPB, 0, stream>>>(x, W1, hs1, cursor, NB, N);
    k_partscatter<<<NS, TPB, 0, stream>>>(src, dst, cursor, pairs2, NB, E);
    k_degree2    <<<NB, TPB, 0, stream>>>(pairs2, cursor, cnt, off, dinv, hs1, N);
    k_gather1    <<<nbN8, TPB, 0, stream>>>(off, cnt, (const int*)pairs2, hs1, dinv, b1, W2, hs2, N);
    k_gather2    <<<nbN8, TPB, 0, stream>>>(off, cnt, (const int*)pairs2, hs2, dinv, b2, W3, hs3, N);
    k_gather3    <<<nbN8, TPB, 0, stream>>>(off, cnt, (const int*)pairs2, hs3, dinv, b3, out, N);
}